// Round 3
// baseline (130.624 us; speedup 1.0000x reference)
//
#include <hip/hip_runtime.h>
#include <hip/hip_bf16.h>

// Embedding lookup: out[token, :] = W[x[token], :]
//   x: int32 [4096]   (BATCH*POS = 2*2048)
//   W: fp32  [32000, 768]
//   out: fp32 [4096, 768]
//
// 768 floats per row = 192 float4. Block = 256 threads handling 4 tokens
// (4*192 = 768 float4 = 3 per thread) -> 1024 blocks instead of 4096,
// 3 independent copies per thread for ILP. Stores are non-temporal
// (out is written once and never re-read by this kernel).
// NOTE: __builtin_nontemporal_store needs a native vector type, not HIP's
// float4 class -> use ext_vector_type(4).

typedef float fvec4 __attribute__((ext_vector_type(4)));

#define EMBED_DIM    768
#define V4_PER_ROW   (EMBED_DIM / 4)     // 192
#define TOK_PER_BLK  4
#define V4_PER_BLK   (V4_PER_ROW * TOK_PER_BLK)  // 768

__global__ __launch_bounds__(256)
void embed_gather_kernel(const int* __restrict__ x,
                         const fvec4* __restrict__ W,
                         fvec4* __restrict__ out) {
    const int tid = threadIdx.x;
    const int tok0 = blockIdx.x * TOK_PER_BLK;

#pragma unroll
    for (int i = 0; i < V4_PER_BLK / 256; ++i) {
        const int idx = tid + i * 256;              // 0..767 within block
        const int tok = tok0 + idx / V4_PER_ROW;    // const-div -> magic mul
        const int col = idx % V4_PER_ROW;
        const int row = x[tok];
        const fvec4 v = W[(size_t)row * V4_PER_ROW + col];
        __builtin_nontemporal_store(v, &out[(size_t)tok * V4_PER_ROW + col]);
    }
}

extern "C" void kernel_launch(void* const* d_in, const int* in_sizes, int n_in,
                              void* d_out, int out_size, void* d_ws, size_t ws_size,
                              hipStream_t stream) {
    const int*   x = (const int*)d_in[0];        // [4096] token ids
    const fvec4* W = (const fvec4*)d_in[1];      // [32000 * 192] float4
    fvec4*     out = (fvec4*)d_out;              // [4096 * 192] float4

    const int n_tokens = in_sizes[0];            // 4096
    const int n_blocks = n_tokens / TOK_PER_BLK; // 1024
    embed_gather_kernel<<<n_blocks, 256, 0, stream>>>(x, W, out);
}